// Round 5
// baseline (20996.617 us; speedup 1.0000x reference)
//
#include <hip/hip_runtime.h>
#include <hip/hip_bf16.h>

// ACOPF Gauss-Newton, matrix-free CGLS, single-workgroup LDS-resident solver.
// R5: fused (J^T J + ridge) operator in ONE gather phase (2-hop local row-dot
// recompute, from R4) + the R3 standard-PCG recurrence that passed (alpha =
// gamma/delta, residual replacement WITHOUT restart), tol 1e-11.
// 3 barrier phases per CG iteration (R3 had 4; R4's 2-phase CG-Gear was
// numerically too loose for the near-null isolated-bus directions).

#define NBUS 1000
#define NLINE 2000
#define NE   (2*NLINE)
#define NGEN 100
#define NLOAD 500
#define NTH 1024
#define NWAVE (NTH/64)
#define MAXSTEPS 10
#define KCG_MAX 600
#define RIDGE_F 1e-6f
#define TOL_REL 1e-11

struct Ws {
  int   vm_pos[NBUS];
  int   va_pos[NBUS];
  float Pspec[NBUS];
  float Qspec[NBUS];
  float Vgb[NBUS];
};

// ---- dtype-robust load/store (auto-detected bf16 vs f32) -------------------
__device__ __forceinline__ float rdf(const void* p, int i, int bf) {
  if (bf) {
    unsigned int u = ((unsigned int)(((const unsigned short*)p)[i])) << 16;
    return __uint_as_float(u);
  }
  return ((const float*)p)[i];
}
__device__ __forceinline__ void wrf(void* p, int i, float v, int bf) {
  if (bf) {
    unsigned int u = __float_as_uint(v);
    unsigned int r = (u + 0x7fffu + ((u >> 16) & 1u)) >> 16;  // RNE
    ((unsigned short*)p)[i] = (unsigned short)r;
  } else {
    ((float*)p)[i] = v;
  }
}
__device__ __forceinline__ int detect_bf(const void* p) {
  const unsigned short* h = (const unsigned short*)p;
  int ok = 1;
#pragma unroll
  for (int i = 0; i < 8; ++i) {
    float v = __uint_as_float(((unsigned int)h[i]) << 16);
    ok &= (v > 0.25f && v < 8.0f) ? 1 : 0;
  }
  return ok;
}
__device__ __forceinline__ int lbound(const int* a, int n, int v) {
  int lo = 0, hi = n;
  while (lo < hi) { int m = (lo + hi) >> 1; if (a[m] < v) lo = m + 1; else hi = m; }
  return lo;
}

// ---- line admittance (used ONCE at CSR build) ------------------------------
struct In {
  const void *lg, *lb, *tp, *sh, *ch;
  const int *lf, *lt;
  int bf;
};
struct LineY { int f, t; float ffr, ffi, ttr, tti, ftr, fti, tfr, tfi; };

__device__ __forceinline__ LineY line_y(const In& I, int l) {
  LineY L;
  float g = rdf(I.lg, l, I.bf), b = rdf(I.lb, l, I.bf);
  float t = rdf(I.tp, l, I.bf), s = rdf(I.sh, l, I.bf);
  float c = rdf(I.ch, l, I.bf) * 0.5f;
  float sn, cs;
  __sincosf(s, &sn, &cs);
  float it = 1.0f / t, it2 = it * it;
  L.f = I.lf[l]; L.t = I.lt[l];
  L.ffr = g * it2;                 L.ffi = (b + c) * it2;
  L.ttr = g;                       L.tti = b + c;
  L.ftr = -(g * cs - b * sn) * it; L.fti = -(g * sn + b * cs) * it;
  L.tfr = -(g * cs + b * sn) * it; L.tfi = -(b * cs - g * sn) * it;
  return L;
}

// single-barrier block sum; caller MUST alternate red buffers (ping-pong):
// a thread may still be reading buffer A after the internal barrier while
// another thread enters the next reduction — which must therefore use buffer B.
__device__ __forceinline__ double blk_sum1(double v, double* red) {
#pragma unroll
  for (int o = 32; o > 0; o >>= 1) v += __shfl_down(v, o, 64);
  if ((threadIdx.x & 63) == 0) red[threadIdx.x >> 6] = v;
  __syncthreads();
  double s = 0.0;
#pragma unroll
  for (int w = 0; w < NWAVE; ++w) s += red[w];
  return s;
}

// ---- setup -----------------------------------------------------------------
__global__ void setup_k(const void* lg, const void* Pg, const void* Vg,
                        const void* Pl, const void* Ql,
                        const int* gen_b, const int* load_b, const int* refp,
                        Ws* __restrict__ W) {
  int bf = detect_bf(lg);
  int t = blockIdx.x * blockDim.x + threadIdx.x;
  int ref = refp[0];
  if (t < NBUS) {
    int gl = lbound(gen_b, NGEN, t);
    int isg = (gl < NGEN && gen_b[gl] == t) ? 1 : 0;
    int ll = lbound(load_b, NLOAD, t);
    int isl = (ll < NLOAD && load_b[ll] == t) ? 1 : 0;
    W->vm_pos[t] = isg ? -1 : (t - gl);
    W->va_pos[t] = (t == ref) ? -1 : (t - ((t > ref) ? 1 : 0));
    float ps = 0.f, qs = 0.f;
    if (isg) ps += rdf(Pg, gl, bf);
    if (isl) { ps += rdf(Pl, ll, bf); qs += rdf(Ql, ll, bf); }
    W->Pspec[t] = ps;
    W->Qspec[t] = qs;
    W->Vgb[t] = isg ? rdf(Vg, gl, bf) : 1.0f;
  }
}

// ---- the whole solve in one workgroup --------------------------------------
__global__ void __launch_bounds__(NTH)
solver_k(const void* lg, const void* lb, const void* shg, const void* shb,
         const void* tp, const void* sh, const void* ch, const void* limits,
         const int* lf, const int* lt, const int* gen_b, const int* refp,
         const Ws* __restrict__ W, void* __restrict__ out) {
  __shared__ int rs_[NBUS + 1];
  __shared__ int scan_[NTH];
  __shared__ int scan2_[NTH];
  __shared__ int cur_[NBUS];
  __shared__ unsigned short cidx_[NE];
  __shared__ float2 fwd_[NE];   // Y_kj (row k -> col j)
  __shared__ float2 rev_[NE];   // Y_jk
  __shared__ float2 ab_[NBUS];  // per-bus V (re,im)
  __shared__ float2 dv_[NBUS];  // staging (perturbation / row-weights / PQ)
  __shared__ float2 mk_[NBUS];  // (mnr, mng) row masks
  __shared__ float2 ci_[NBUS];  // per-bus injected current I (re,im)
  __shared__ float2 gb_[NBUS];  // per-bus diag Y_kk (G,B)
  __shared__ double red_[2][NWAVE];

  const int tid = threadIdx.x;
  const bool own = (tid < NBUS);
  In I;
  I.lg = lg; I.lb = lb; I.tp = tp; I.sh = sh; I.ch = ch;
  I.lf = lf; I.lt = lt;
  I.bf = detect_bf(lg);
  const int bf = I.bf;

  // --- per-bus constants into registers + LDS ---
  int vp = -1, ap = -1;
  float mng = 0.f, mnr = 0.f, Pspec = 0.f, Qspec = 0.f, Vgb = 1.f;
  if (own) {
    vp = W->vm_pos[tid]; ap = W->va_pos[tid];
    mng = (vp >= 0) ? 1.f : 0.f;
    mnr = (ap >= 0) ? 1.f : 0.f;
    Pspec = W->Pspec[tid]; Qspec = W->Qspec[tid]; Vgb = W->Vgb[tid];
    mk_[tid] = make_float2(mnr, mng);
    gb_[tid] = make_float2(rdf(shg, tid, bf), rdf(shb, tid, bf));
  }
  scan_[tid] = 0;
  __syncthreads();
  for (int l = tid; l < NLINE; l += NTH) {
    atomicAdd(&scan_[lf[l]], 1);
    atomicAdd(&scan_[lt[l]], 1);
  }
  __syncthreads();
  {
    int* src = scan_; int* dst = scan2_;
    for (int off = 1; off < NTH; off <<= 1) {
      int v = src[tid] + ((tid >= off) ? src[tid - off] : 0);
      dst[tid] = v;
      __syncthreads();
      int* t = src; src = dst; dst = t;
    }
    if (tid == 0) rs_[0] = 0;
    if (own) rs_[tid + 1] = src[tid];
  }
  __syncthreads();
  if (own) cur_[tid] = rs_[tid];
  __syncthreads();
  for (int l = tid; l < NLINE; l += NTH) {
    LineY L = line_y(I, l);
    int pf = atomicAdd(&cur_[L.f], 1);
    cidx_[pf] = (unsigned short)L.t;
    fwd_[pf] = make_float2(L.ftr, L.fti);
    rev_[pf] = make_float2(L.tfr, L.tfi);
    int pt = atomicAdd(&cur_[L.t], 1);
    cidx_[pt] = (unsigned short)L.f;
    fwd_[pt] = make_float2(L.tfr, L.tfi);
    rev_[pt] = make_float2(L.ftr, L.fti);
    atomicAdd(&gb_[L.f].x, L.ffr); atomicAdd(&gb_[L.f].y, L.ffi);
    atomicAdd(&gb_[L.t].x, L.ttr); atomicAdd(&gb_[L.t].y, L.tti);
  }
  __syncthreads();
  float Gkk = 0.f, Bkk = 0.f;
  int rs0 = 0, rs1 = 0;
  if (own) { Gkk = gb_[tid].x; Bkk = gb_[tid].y; rs0 = rs_[tid]; rs1 = rs_[tid + 1]; }
  __syncthreads();

  float xvm = 1.f, xva = 0.f;
  int par = 0;

  for (int outer = 0; outer < MAXSTEPS; ++outer) {
    // --- phase A: state ---
    float av = 0.f, bv = 0.f, ca = 1.f, sa = 0.f;
    if (own) {
      float Vm = (vp >= 0) ? xvm : Vgb;
      float Va = (ap >= 0) ? xva : 0.f;
      __sincosf(Va, &sa, &ca);
      av = Vm * ca; bv = Vm * sa;
      ab_[tid] = make_float2(av, bv);
    }
    __syncthreads();
    // --- phase B: currents, residual rows, 2x2 block-Jacobi, stage weights ---
    float cI = 0.f, dI = 0.f, wP = 0.f, wQ = 0.f;
    float M11 = 0.f, M12 = 0.f, M22 = 0.f;
    if (own) {
      cI = Gkk * av - Bkk * bv; dI = Gkk * bv + Bkk * av;
      for (int e = rs0; e < rs1; ++e) {
        int j = cidx_[e]; float2 f = fwd_[e], v = ab_[j];
        cI += f.x * v.x - f.y * v.y; dI += f.x * v.y + f.y * v.x;
      }
      ci_[tid] = make_float2(cI, dI);
      float P = av * cI + bv * dI - Pspec;
      float Q = bv * cI - av * dI - Qspec;
      wP = mnr * P; wQ = mng * Q;
      dv_[tid] = make_float2(wP, wQ);
      // block-Jacobi 2x2 of (J^T J + ridge)
      float w1r = ca * cI + sa * dI, w1i = sa * cI - ca * dI;
      float mr = Gkk * ca - Bkk * sa, mi = -(Gkk * sa + Bkk * ca);
      float ur0 = av * mr - bv * mi, ui0 = av * mi + bv * mr;
      float Tr = w1r + ur0, Ti = w1i + ui0;
      float w2r = av * dI - bv * cI, w2i = av * cI + bv * dI;
      float wr0 = Gkk * av - Bkk * bv, wi0 = Gkk * bv + Bkk * av;
      float zr0 = av * wr0 + bv * wi0, zi0 = bv * wr0 - av * wi0;
      float Uor = w2r + zi0, Uoi = w2i - zr0;
      float Avv = mnr * Tr * Tr + mng * Ti * Ti;
      float Aaa = mnr * Uor * Uor + mng * Uoi * Uoi;
      float Ava = mnr * Tr * Uor + mng * Ti * Uoi;
      for (int e = rs0; e < rs1; ++e) {
        int j = cidx_[e]; float2 r = rev_[e], vj = ab_[j], mj = mk_[j];
        float mrr = r.x * ca - r.y * sa, mii = -(r.x * sa + r.y * ca);
        float ur = vj.x * mrr - vj.y * mii, ui = vj.x * mii + vj.y * mrr;
        float wr = r.x * av - r.y * bv, wi = r.x * bv + r.y * av;
        float zr = vj.x * wr + vj.y * wi, zi = vj.y * wr - vj.x * wi;
        Avv += mj.x * ur * ur + mj.y * ui * ui;
        Aaa += mj.x * zi * zi + mj.y * zr * zr;
        Ava += mj.x * ur * zi - mj.y * ui * zr;
      }
      float A11 = Avv + RIDGE_F, A22 = Aaa + RIDGE_F;
      if (vp >= 0 && ap >= 0) {
        float id = 1.f / (A11 * A22 - Ava * Ava);
        M11 = A22 * id; M22 = A11 * id; M12 = -Ava * id;
      } else if (vp >= 0) M11 = 1.f / A11;
      else if (ap >= 0)  M22 = 1.f / A22;
    }
    __syncthreads();
    // --- phase C: g0 = J^T r (adjoint gather of staged row weights) ---
    float g0vm = 0.f, g0va = 0.f;
    if (own) {
      float wrii = Gkk * av + Bkk * bv, wiii = Gkk * bv - Bkk * av; // V conj(Ykk)
      float sda = wP * cI - wQ * dI + wP * wrii + wQ * wiii;
      float sdb = wP * dI + wQ * cI + wP * wiii - wQ * wrii;
      for (int e = rs0; e < rs1; ++e) {
        int j = cidx_[e]; float2 r = rev_[e], abj = ab_[j], qj = dv_[j];
        float wr = abj.x * r.x + abj.y * r.y, wi = abj.y * r.x - abj.x * r.y;
        sda += qj.x * wr + qj.y * wi; sdb += qj.x * wi - qj.y * wr;
      }
      g0vm = mng * (ca * sda + sa * sdb);
      g0va = mnr * (-bv * sda + av * sdb);
    }
    __syncthreads();   // g0 gather reads of dv_ done before CG stages overwrite

    // fused operator: stage perturb(u), barrier, w = (J^T J + ridge) u via
    // local recompute of own + neighbor row-dots (identical algebra to the
    // R3 JVP->VJP composition; verified term-by-term).
    auto opA = [&](float uvm, float uva, float& wvm, float& wva) {
      if (own) {
        float da = uvm * ca - uva * bv;
        float db = uvm * sa + uva * av;
        dv_[tid] = make_float2(da, db);
      }
      __syncthreads();
      float sda = 0.f, sdb = 0.f;
      if (own) {
        float2 dvi = dv_[tid];
        float dc = Gkk * dvi.x - Bkk * dvi.y, dd = Gkk * dvi.y + Bkk * dvi.x;
        for (int e = rs0; e < rs1; ++e) {
          int k = cidx_[e]; float2 f = fwd_[e], vk = dv_[k];
          dc += f.x * vk.x - f.y * vk.y; dd += f.x * vk.y + f.y * vk.x;
        }
        float dP = dvi.x * cI + av * dc + dvi.y * dI + bv * dd;
        float dQ = dvi.y * cI + bv * dc - dvi.x * dI - av * dd;
        float qP = mnr * dP, qQ = mng * dQ;
        float wrii = Gkk * av + Bkk * bv, wiii = Gkk * bv - Bkk * av;
        sda = qP * cI - qQ * dI + qP * wrii + qQ * wiii;
        sdb = qP * dI + qQ * cI + qP * wiii - qQ * wrii;
        for (int e = rs0; e < rs1; ++e) {
          int j = cidx_[e];
          float2 abj = ab_[j], cij = ci_[j], gbj = gb_[j], mj = mk_[j], dvj = dv_[j];
          int rj0 = rs_[j], rj1 = rs_[j + 1];
          float dcj = gbj.x * dvj.x - gbj.y * dvj.y;
          float ddj = gbj.x * dvj.y + gbj.y * dvj.x;
          for (int f = rj0; f < rj1; ++f) {
            int k = cidx_[f]; float2 fc = fwd_[f], vk = dv_[k];
            dcj += fc.x * vk.x - fc.y * vk.y; ddj += fc.x * vk.y + fc.y * vk.x;
          }
          float dPj = dvj.x * cij.x + abj.x * dcj + dvj.y * cij.y + abj.y * ddj;
          float dQj = dvj.y * cij.x + abj.y * dcj - dvj.x * cij.y - abj.x * ddj;
          float qPj = mj.x * dPj, qQj = mj.y * dQj;
          float2 r = rev_[e];
          float wr = abj.x * r.x + abj.y * r.y, wi = abj.y * r.x - abj.x * r.y;
          sda += qPj * wr + qQj * wi; sdb += qPj * wi - qQj * wr;
        }
      }
      wvm = mng * (ca * sda + sa * sdb) + RIDGE_F * uvm;
      wva = mnr * (-bv * sda + av * sdb) + RIDGE_F * uva;
    };

    // --- standard PCG (R3 recurrence), 3 barrier phases / iter ---
    float rvm = g0vm, rva = g0va, dxvm = 0.f, dxva = 0.f;
    float zvm = M11 * rvm + M12 * rva, zva = M12 * rvm + M22 * rva;
    float pvm = zvm, pva = zva;
    double part = own ? ((double)rvm * zvm + (double)rva * zva) : 0.0;
    double gamma = blk_sum1(part, red_[par]); par ^= 1;
    const double gamma0 = gamma;

    if (gamma0 > 0.0) {
      for (int it = 0; it < KCG_MAX; ++it) {
        float wvm, wva;
        opA(pvm, pva, wvm, wva);                       // barrier 1 (stage)
        double dpart = own ? ((double)pvm * wvm + (double)pva * wva) : 0.0;
        double delta = blk_sum1(dpart, red_[par]); par ^= 1;   // barrier 2
        if (!(delta > 0.0)) break;
        float af = (float)(gamma / delta);
        dxvm += af * pvm; dxva += af * pva;
        rvm -= af * wvm; rva -= af * wva;
        if ((it & 63) == 63) {
          // residual replacement (keep p): r = g0 - (A + ridge) dx
          float tvm, tva;
          opA(dxvm, dxva, tvm, tva);
          rvm = g0vm - tvm; rva = g0va - tva;
          __syncthreads();   // opA gather reads done before next stage write
        }
        double gpart = 0.0;
        if (own) {
          zvm = M11 * rvm + M12 * rva; zva = M12 * rvm + M22 * rva;
          gpart = (double)rvm * zvm + (double)rva * zva;
        }
        double gamma2 = blk_sum1(gpart, red_[par]); par ^= 1;  // barrier 3
        if (gamma2 <= gamma0 * TOL_REL || !(gamma2 > 0.0)) break;
        float bfac = (float)(gamma2 / gamma);
        pvm = zvm + bfac * pvm; pva = zva + bfac * pva;
        gamma = gamma2;
      }
    }
    if (own) { xvm -= dxvm; xva -= dxva; }
    __syncthreads();
  }

  // ---- final outputs ----
  float Vmf = 1.f, Vaf = 0.f, av = 0.f, bv = 0.f, cI = 0.f, dI = 0.f;
  if (own) {
    Vmf = (vp >= 0) ? xvm : Vgb;
    Vaf = (ap >= 0) ? xva : 0.f;
    float sn, cs;
    __sincosf(Vaf, &sn, &cs);
    av = Vmf * cs; bv = Vmf * sn;
    ab_[tid] = make_float2(av, bv);
  }
  __syncthreads();
  float P = 0.f, Q = 0.f;
  if (own) {
    cI = Gkk * av - Bkk * bv; dI = Gkk * bv + Bkk * av;
    for (int e = rs0; e < rs1; ++e) {
      int j = cidx_[e]; float2 f = fwd_[e], v = ab_[j];
      cI += f.x * v.x - f.y * v.y; dI += f.x * v.y + f.y * v.x;
    }
    P = av * cI + bv * dI - Pspec;
    Q = bv * cI - av * dI - Qspec;
    dv_[tid] = make_float2(P, Q);
  }
  __syncthreads();
  double rpart = own ? (double)(mnr * P * P + mng * Q * Q) : 0.0;
  double rsum = blk_sum1(rpart, red_[par]); par ^= 1;
  if (own) {
    wrf(out, tid, Vmf, bf);
    wrf(out, NBUS + tid, Vaf, bf);
    float vmin = rdf(limits, 2 * tid, bf), vmax = rdf(limits, 2 * tid + 1, bf);
    float viol = fmaxf(Vmf - vmax, 0.f) + fmaxf(vmin - Vmf, 0.f);
    wrf(out, 2103 + tid, viol, bf);
  }
  if (tid < NGEN) wrf(out, 2000 + tid, dv_[gen_b[tid]].y, bf);
  if (tid == 0) {
    int ref = refp[0];
    wrf(out, 2100, dv_[ref].x, bf);
    wrf(out, 2101, dv_[ref].y, bf);
    wrf(out, 2102, (float)rsum, bf);
  }
}

extern "C" void kernel_launch(void* const* d_in, const int* in_sizes, int n_in,
                              void* d_out, int out_size, void* d_ws, size_t ws_size,
                              hipStream_t stream) {
  const void* line_g   = d_in[0];
  const void* line_b   = d_in[1];
  const void* shunt_g  = d_in[2];
  const void* shunt_b  = d_in[3];
  const void* tap      = d_in[4];
  const void* shift    = d_in[5];
  const void* charging = d_in[6];
  const void* P_gen    = d_in[7];
  const void* V_gen    = d_in[8];
  const void* P_load   = d_in[9];
  const void* Q_load   = d_in[10];
  const void* limits   = d_in[11];
  const int* line_from = (const int*)d_in[12];
  const int* line_to   = (const int*)d_in[13];
  const int* gen_b     = (const int*)d_in[14];
  const int* load_b    = (const int*)d_in[15];
  const int* refp      = (const int*)d_in[18];

  if (ws_size < sizeof(Ws)) return;
  Ws* W = (Ws*)d_ws;

  setup_k<<<dim3(8), dim3(256), 0, stream>>>(line_g, P_gen, V_gen, P_load, Q_load,
                                             gen_b, load_b, refp, W);
  solver_k<<<dim3(1), dim3(NTH), 0, stream>>>(line_g, line_b, shunt_g, shunt_b,
                                              tap, shift, charging, limits,
                                              line_from, line_to, gen_b, refp,
                                              W, d_out);
}

// Round 6
// 5885.871 us; speedup vs baseline: 3.5673x; 3.5673x over previous
//
#include <hip/hip_runtime.h>
#include <hip/hip_bf16.h>

// ACOPF Gauss-Newton, matrix-free CGLS, single-workgroup LDS-resident solver.
// R6 = R3 arithmetic (separate 1-hop JVP/VJP gathers, standard PCG, 2x2
// block-Jacobi, RR-keep-p every 64, tol 1e-11) +
//  (a) degree-sorted bus->thread ownership (counting sort) so each wave's
//      edge loop runs ~avg-degree iterations instead of max-degree (~2.5x
//      less exec-masked LDS work), and
//  (b) 3 barrier phases/iter: stage-p | JVP+stage-q+delta-reduce | VJP+gamma-
//      reduce (own-bus values kept in registers, never re-read from LDS).

#define NBUS 1000
#define NLINE 2000
#define NE   (2*NLINE)
#define NGEN 100
#define NLOAD 500
#define NTH 1024
#define NWAVE (NTH/64)
#define MAXSTEPS 10
#define KCG_MAX 600
#define RIDGE_F 1e-6f
#define TOL_REL 1e-11

struct Ws {
  int   vm_pos[NBUS];
  int   va_pos[NBUS];
  float Pspec[NBUS];
  float Qspec[NBUS];
  float Vgb[NBUS];
};

// ---- dtype-robust load/store (auto-detected bf16 vs f32) -------------------
__device__ __forceinline__ float rdf(const void* p, int i, int bf) {
  if (bf) {
    unsigned int u = ((unsigned int)(((const unsigned short*)p)[i])) << 16;
    return __uint_as_float(u);
  }
  return ((const float*)p)[i];
}
__device__ __forceinline__ void wrf(void* p, int i, float v, int bf) {
  if (bf) {
    unsigned int u = __float_as_uint(v);
    unsigned int r = (u + 0x7fffu + ((u >> 16) & 1u)) >> 16;  // RNE
    ((unsigned short*)p)[i] = (unsigned short)r;
  } else {
    ((float*)p)[i] = v;
  }
}
__device__ __forceinline__ int detect_bf(const void* p) {
  const unsigned short* h = (const unsigned short*)p;
  int ok = 1;
#pragma unroll
  for (int i = 0; i < 8; ++i) {
    float v = __uint_as_float(((unsigned int)h[i]) << 16);
    ok &= (v > 0.25f && v < 8.0f) ? 1 : 0;
  }
  return ok;
}
__device__ __forceinline__ int lbound(const int* a, int n, int v) {
  int lo = 0, hi = n;
  while (lo < hi) { int m = (lo + hi) >> 1; if (a[m] < v) lo = m + 1; else hi = m; }
  return lo;
}

// ---- line admittance (used ONCE at CSR build) ------------------------------
struct In {
  const void *lg, *lb, *tp, *sh, *ch;
  const int *lf, *lt;
  int bf;
};
struct LineY { int f, t; float ffr, ffi, ttr, tti, ftr, fti, tfr, tfi; };

__device__ __forceinline__ LineY line_y(const In& I, int l) {
  LineY L;
  float g = rdf(I.lg, l, I.bf), b = rdf(I.lb, l, I.bf);
  float t = rdf(I.tp, l, I.bf), s = rdf(I.sh, l, I.bf);
  float c = rdf(I.ch, l, I.bf) * 0.5f;
  float sn, cs;
  __sincosf(s, &sn, &cs);
  float it = 1.0f / t, it2 = it * it;
  L.f = I.lf[l]; L.t = I.lt[l];
  L.ffr = g * it2;                 L.ffi = (b + c) * it2;
  L.ttr = g;                       L.tti = b + c;
  L.ftr = -(g * cs - b * sn) * it; L.fti = -(g * sn + b * cs) * it;
  L.tfr = -(g * cs + b * sn) * it; L.tfi = -(b * cs - g * sn) * it;
  return L;
}

// single-barrier block sum; caller alternates red buffers (ping-pong).
__device__ __forceinline__ double blk_sum1(double v, double* red) {
#pragma unroll
  for (int o = 32; o > 0; o >>= 1) v += __shfl_down(v, o, 64);
  if ((threadIdx.x & 63) == 0) red[threadIdx.x >> 6] = v;
  __syncthreads();
  double s = 0.0;
#pragma unroll
  for (int w = 0; w < NWAVE; ++w) s += red[w];
  return s;
}

// ---- setup -----------------------------------------------------------------
__global__ void setup_k(const void* lg, const void* Pg, const void* Vg,
                        const void* Pl, const void* Ql,
                        const int* gen_b, const int* load_b, const int* refp,
                        Ws* __restrict__ W) {
  int bf = detect_bf(lg);
  int t = blockIdx.x * blockDim.x + threadIdx.x;
  int ref = refp[0];
  if (t < NBUS) {
    int gl = lbound(gen_b, NGEN, t);
    int isg = (gl < NGEN && gen_b[gl] == t) ? 1 : 0;
    int ll = lbound(load_b, NLOAD, t);
    int isl = (ll < NLOAD && load_b[ll] == t) ? 1 : 0;
    W->vm_pos[t] = isg ? -1 : (t - gl);
    W->va_pos[t] = (t == ref) ? -1 : (t - ((t > ref) ? 1 : 0));
    float ps = 0.f, qs = 0.f;
    if (isg) ps += rdf(Pg, gl, bf);
    if (isl) { ps += rdf(Pl, ll, bf); qs += rdf(Ql, ll, bf); }
    W->Pspec[t] = ps;
    W->Qspec[t] = qs;
    W->Vgb[t] = isg ? rdf(Vg, gl, bf) : 1.0f;
  }
}

// ---- the whole solve in one workgroup --------------------------------------
__global__ void __launch_bounds__(NTH)
solver_k(const void* lg, const void* lb, const void* shg, const void* shb,
         const void* tp, const void* sh, const void* ch, const void* limits,
         const int* lf, const int* lt, const int* gen_b, const int* refp,
         const Ws* __restrict__ W, void* __restrict__ out) {
  __shared__ int rs_[NBUS + 1];
  __shared__ int scan_[NTH];
  __shared__ int scan2_[NTH];
  __shared__ int cur_[NBUS];
  __shared__ int sigma_[NBUS];          // degree-sorted bus ownership
  __shared__ int hist_[32];
  __shared__ int base_[32];
  __shared__ unsigned short cidx_[NE];
  __shared__ float2 fwd_[NE];           // Y_kj
  __shared__ float2 rev_[NE];           // Y_jk
  __shared__ float2 ab_[NBUS];          // per-bus V (re,im)
  __shared__ float2 dv_[NBUS];          // staging A (perturb / g0 seeds / PQ)
  __shared__ float2 dv2_[NBUS];         // staging B (q-row seeds)
  __shared__ float2 mk_[NBUS];          // (mnr, mng)
  __shared__ float2 gb_[NBUS];          // diag Y_kk accumulator
  __shared__ double red_[2][NWAVE];

  const int tid = threadIdx.x;
  In I;
  I.lg = lg; I.lb = lb; I.tp = tp; I.sh = sh; I.ch = ch;
  I.lf = lf; I.lt = lt;
  I.bf = detect_bf(lg);
  const int bf = I.bf;

  // --- bus-indexed constants ---
  if (tid < NBUS) {
    int vpb = W->vm_pos[tid], apb = W->va_pos[tid];
    mk_[tid] = make_float2((apb >= 0) ? 1.f : 0.f, (vpb >= 0) ? 1.f : 0.f);
    gb_[tid] = make_float2(rdf(shg, tid, bf), rdf(shb, tid, bf));
  }
  if (tid < 32) hist_[tid] = 0;
  scan_[tid] = 0;
  __syncthreads();
  for (int l = tid; l < NLINE; l += NTH) {
    atomicAdd(&scan_[lf[l]], 1);
    atomicAdd(&scan_[lt[l]], 1);
  }
  __syncthreads();
  // capture degree + histogram BEFORE the prefix sum clobbers scan_
  const int mydeg = (tid < NBUS) ? scan_[tid] : -1;
  if (tid < NBUS) atomicAdd(&hist_[mydeg < 31 ? mydeg : 31], 1);
  // inclusive scan (Hillis-Steele ping-pong) -> rs_
  {
    int* src = scan_; int* dst = scan2_;
    for (int off = 1; off < NTH; off <<= 1) {
      int v = src[tid] + ((tid >= off) ? src[tid - off] : 0);
      dst[tid] = v;
      __syncthreads();
      int* t = src; src = dst; dst = t;
    }
    if (tid == 0) rs_[0] = 0;
    if (tid < NBUS) rs_[tid + 1] = src[tid];
  }
  __syncthreads();
  if (tid == 0) {
    int run = 0;
    for (int k = 0; k < 32; ++k) { base_[k] = run; run += hist_[k]; }
  }
  if (tid < NBUS) cur_[tid] = rs_[tid];
  __syncthreads();
  if (tid < NBUS) {
    int pos = atomicAdd(&base_[mydeg < 31 ? mydeg : 31], 1);
    sigma_[pos] = tid;
  }
  __syncthreads();
  // --- CSR fill + diag Y_kk (the only global loads in the kernel) ---
  for (int l = tid; l < NLINE; l += NTH) {
    LineY L = line_y(I, l);
    int pf = atomicAdd(&cur_[L.f], 1);
    cidx_[pf] = (unsigned short)L.t;
    fwd_[pf] = make_float2(L.ftr, L.fti);
    rev_[pf] = make_float2(L.tfr, L.tfi);
    int pt = atomicAdd(&cur_[L.t], 1);
    cidx_[pt] = (unsigned short)L.f;
    fwd_[pt] = make_float2(L.tfr, L.tfi);
    rev_[pt] = make_float2(L.ftr, L.fti);
    atomicAdd(&gb_[L.f].x, L.ffr); atomicAdd(&gb_[L.f].y, L.ffi);
    atomicAdd(&gb_[L.t].x, L.ttr); atomicAdd(&gb_[L.t].y, L.tti);
  }
  __syncthreads();
  // --- ownership: thread tid owns bus b = sigma_[tid] (degree-homogeneous waves) ---
  const int b = (tid < NBUS) ? sigma_[tid] : -1;
  const bool own = (b >= 0);
  int vp = -1, ap = -1, rs0 = 0, rs1 = 0;
  float mng = 0.f, mnr = 0.f, Pspec = 0.f, Qspec = 0.f, Vgb = 1.f, Gkk = 0.f, Bkk = 0.f;
  if (own) {
    vp = W->vm_pos[b]; ap = W->va_pos[b];
    mng = (vp >= 0) ? 1.f : 0.f;
    mnr = (ap >= 0) ? 1.f : 0.f;
    Pspec = W->Pspec[b]; Qspec = W->Qspec[b]; Vgb = W->Vgb[b];
    Gkk = gb_[b].x; Bkk = gb_[b].y;
    rs0 = rs_[b]; rs1 = rs_[b + 1];
  }

  float xvm = 1.f, xva = 0.f;
  int par = 0;

  for (int outer = 0; outer < MAXSTEPS; ++outer) {
    // --- phase A: state ---
    float av = 0.f, bv = 0.f, ca = 1.f, sa = 0.f;
    if (own) {
      float Vm = (vp >= 0) ? xvm : Vgb;
      float Va = (ap >= 0) ? xva : 0.f;
      __sincosf(Va, &sa, &ca);
      av = Vm * ca; bv = Vm * sa;
      ab_[b] = make_float2(av, bv);
    }
    __syncthreads();
    // --- phase B: currents, residual rows (stage g0 seeds), 2x2 block-Jacobi ---
    float cI = 0.f, dI = 0.f, wPp = 0.f, wQq = 0.f;
    float M11 = 0.f, M12 = 0.f, M22 = 0.f;
    if (own) {
      cI = Gkk * av - Bkk * bv; dI = Gkk * bv + Bkk * av;
      for (int e = rs0; e < rs1; ++e) {
        int j = cidx_[e]; float2 f = fwd_[e], v = ab_[j];
        cI += f.x * v.x - f.y * v.y; dI += f.x * v.y + f.y * v.x;
      }
      float P = av * cI + bv * dI - Pspec;
      float Q = bv * cI - av * dI - Qspec;
      wPp = mnr * P; wQq = mng * Q;
      dv_[b] = make_float2(wPp * av + wQq * bv, wPp * bv - wQq * av);
      // block-Jacobi 2x2 of (J^T J + ridge)
      float w1r = ca * cI + sa * dI, w1i = sa * cI - ca * dI;
      float mr = Gkk * ca - Bkk * sa, mi = -(Gkk * sa + Bkk * ca);
      float ur0 = av * mr - bv * mi, ui0 = av * mi + bv * mr;
      float Tr = w1r + ur0, Ti = w1i + ui0;
      float w2r = av * dI - bv * cI, w2i = av * cI + bv * dI;
      float wr0 = Gkk * av - Bkk * bv, wi0 = Gkk * bv + Bkk * av;
      float zr0 = av * wr0 + bv * wi0, zi0 = bv * wr0 - av * wi0;
      float Uor = w2r + zi0, Uoi = w2i - zr0;
      float Avv = mnr * Tr * Tr + mng * Ti * Ti;
      float Aaa = mnr * Uor * Uor + mng * Uoi * Uoi;
      float Ava = mnr * Tr * Uor + mng * Ti * Uoi;
      for (int e = rs0; e < rs1; ++e) {
        int j = cidx_[e]; float2 r = rev_[e], vj = ab_[j], mj = mk_[j];
        float mrr = r.x * ca - r.y * sa, mii = -(r.x * sa + r.y * ca);
        float ur = vj.x * mrr - vj.y * mii, ui = vj.x * mii + vj.y * mrr;
        float wr = r.x * av - r.y * bv, wi = r.x * bv + r.y * av;
        float zr = vj.x * wr + vj.y * wi, zi = vj.y * wr - vj.x * wi;
        Avv += mj.x * ur * ur + mj.y * ui * ui;
        Aaa += mj.x * zi * zi + mj.y * zr * zr;
        Ava += mj.x * ur * zi - mj.y * ui * zr;
      }
      float A11 = Avv + RIDGE_F, A22 = Aaa + RIDGE_F;
      if (vp >= 0 && ap >= 0) {
        float id = 1.f / (A11 * A22 - Ava * Ava);
        M11 = A22 * id; M22 = A11 * id; M12 = -Ava * id;
      } else if (vp >= 0) M11 = 1.f / A11;
      else if (ap >= 0)  M22 = 1.f / A22;
    }
    __syncthreads();
    // --- phase C: g0 = J^T r ---
    float g0vm = 0.f, g0va = 0.f;
    if (own) {
      float cb = wPp * av + wQq * bv, db2 = wPp * bv - wQq * av;
      float sda = wPp * cI - wQq * dI + Gkk * cb + Bkk * db2;
      float sdb = wPp * dI + wQq * cI - Bkk * cb + Gkk * db2;
      for (int e = rs0; e < rs1; ++e) {
        int j = cidx_[e]; float2 r = rev_[e], w = dv_[j];
        sda += r.x * w.x + r.y * w.y; sdb += -r.y * w.x + r.x * w.y;
      }
      g0vm = mng * (ca * sda + sa * sdb);
      g0va = mnr * (-bv * sda + av * sdb);
    }
    // --- PCG init ---
    float rvm = g0vm, rva = g0va, dxvm = 0.f, dxva = 0.f;
    float zvm = M11 * rvm + M12 * rva, zva = M12 * rvm + M22 * rva;
    float pvm = zvm, pva = zva;
    double part = own ? ((double)rvm * zvm + (double)rva * zva) : 0.0;
    double gamma = blk_sum1(part, red_[par]); par ^= 1;   // also fences dv_ reads
    const double gamma0 = gamma;

    if (gamma0 > 0.0) {
      for (int it = 0; it < KCG_MAX; ++it) {
        // --- P1: stage perturb(p) ---
        float da = 0.f, db = 0.f;
        if (own) {
          da = pvm * ca - pva * bv;
          db = pvm * sa + pva * av;
          dv_[b] = make_float2(da, db);
        }
        __syncthreads();
        // --- P2: JVP gather + stage q seeds + delta partial ---
        float qP = 0.f, qQ = 0.f;
        double dpart = 0.0;
        if (own) {
          float dc = Gkk * da - Bkk * db, dd = Gkk * db + Bkk * da;
          for (int e = rs0; e < rs1; ++e) {
            int j = cidx_[e]; float2 f = fwd_[e], v = dv_[j];
            dc += f.x * v.x - f.y * v.y; dd += f.x * v.y + f.y * v.x;
          }
          float dP = da * cI + av * dc + db * dI + bv * dd;
          float dQ = db * cI + bv * dc - da * dI - av * dd;
          qP = mnr * dP; qQ = mng * dQ;
          dv2_[b] = make_float2(qP * av + qQ * bv, qP * bv - qQ * av);
          dpart = (double)qP * dP + (double)qQ * dQ +
                  (double)RIDGE_F * ((double)pvm * pvm + (double)pva * pva);
        }
        double delta = blk_sum1(dpart, red_[par]); par ^= 1;
        if (!(delta > 0.0)) break;
        float af = (float)(gamma / delta);
        // --- P3: VJP gather; r -= af*(J^T q + ridge p); dx += af*p ---
        if (own) {
          dxvm += af * pvm; dxva += af * pva;
          float cb = qP * av + qQ * bv, db2 = qP * bv - qQ * av;
          float sda = qP * cI - qQ * dI + Gkk * cb + Bkk * db2;
          float sdb = qP * dI + qQ * cI - Bkk * cb + Gkk * db2;
          for (int e = rs0; e < rs1; ++e) {
            int j = cidx_[e]; float2 r = rev_[e], w = dv2_[j];
            sda += r.x * w.x + r.y * w.y; sdb += -r.y * w.x + r.x * w.y;
          }
          float yvm = mng * (ca * sda + sa * sdb);
          float yva = mnr * (-bv * sda + av * sdb);
          rvm -= af * (yvm + RIDGE_F * pvm);
          rva -= af * (yva + RIDGE_F * pva);
        }
        // --- residual replacement (keep p) every 64 iters ---
        if ((it & 63) == 63) {
          __syncthreads();   // all VJP reads of dv2_ / prior dv_ use complete
          float tda = 0.f, tdb = 0.f;
          if (own) {
            tda = dxvm * ca - dxva * bv;
            tdb = dxvm * sa + dxva * av;
            dv_[b] = make_float2(tda, tdb);
          }
          __syncthreads();
          float rqP = 0.f, rqQ = 0.f;
          if (own) {
            float dc = Gkk * tda - Bkk * tdb, dd = Gkk * tdb + Bkk * tda;
            for (int e = rs0; e < rs1; ++e) {
              int j = cidx_[e]; float2 f = fwd_[e], v = dv_[j];
              dc += f.x * v.x - f.y * v.y; dd += f.x * v.y + f.y * v.x;
            }
            float dP = tda * cI + av * dc + tdb * dI + bv * dd;
            float dQ = tdb * cI + bv * dc - tda * dI - av * dd;
            rqP = mnr * dP; rqQ = mng * dQ;
            dv2_[b] = make_float2(rqP * av + rqQ * bv, rqP * bv - rqQ * av);
          }
          __syncthreads();
          if (own) {
            float cb = rqP * av + rqQ * bv, db2 = rqP * bv - rqQ * av;
            float sda = rqP * cI - rqQ * dI + Gkk * cb + Bkk * db2;
            float sdb = rqP * dI + rqQ * cI - Bkk * cb + Gkk * db2;
            for (int e = rs0; e < rs1; ++e) {
              int j = cidx_[e]; float2 r = rev_[e], w = dv2_[j];
              sda += r.x * w.x + r.y * w.y; sdb += -r.y * w.x + r.x * w.y;
            }
            float tvm = mng * (ca * sda + sa * sdb);
            float tva = mnr * (-bv * sda + av * sdb);
            rvm = g0vm - tvm - RIDGE_F * dxvm;
            rva = g0va - tva - RIDGE_F * dxva;
          }
        }
        // --- gamma2 reduction + p update ---
        double gpart = 0.0;
        if (own) {
          zvm = M11 * rvm + M12 * rva; zva = M12 * rvm + M22 * rva;
          gpart = (double)rvm * zvm + (double)rva * zva;
        }
        double gamma2 = blk_sum1(gpart, red_[par]); par ^= 1;
        if (gamma2 <= gamma0 * TOL_REL || !(gamma2 > 0.0)) break;
        float bfac = (float)(gamma2 / gamma);
        pvm = zvm + bfac * pvm; pva = zva + bfac * pva;
        gamma = gamma2;
      }
    }
    if (own) { xvm -= dxvm; xva -= dxva; }
    __syncthreads();
  }

  // ---- final outputs ----
  float Vmf = 1.f, Vaf = 0.f, av = 0.f, bv = 0.f, cI = 0.f, dI = 0.f;
  if (own) {
    Vmf = (vp >= 0) ? xvm : Vgb;
    Vaf = (ap >= 0) ? xva : 0.f;
    float sn, cs;
    __sincosf(Vaf, &sn, &cs);
    av = Vmf * cs; bv = Vmf * sn;
    ab_[b] = make_float2(av, bv);
  }
  __syncthreads();
  float P = 0.f, Q = 0.f;
  if (own) {
    cI = Gkk * av - Bkk * bv; dI = Gkk * bv + Bkk * av;
    for (int e = rs0; e < rs1; ++e) {
      int j = cidx_[e]; float2 f = fwd_[e], v = ab_[j];
      cI += f.x * v.x - f.y * v.y; dI += f.x * v.y + f.y * v.x;
    }
    P = av * cI + bv * dI - Pspec;
    Q = bv * cI - av * dI - Qspec;
    dv_[b] = make_float2(P, Q);
  }
  __syncthreads();
  double rpart = own ? (double)(mnr * P * P + mng * Q * Q) : 0.0;
  double rsum = blk_sum1(rpart, red_[par]); par ^= 1;   // also fences dv_ writes
  if (own) {
    wrf(out, b, Vmf, bf);
    wrf(out, NBUS + b, Vaf, bf);
    float vmin = rdf(limits, 2 * b, bf), vmax = rdf(limits, 2 * b + 1, bf);
    float viol = fmaxf(Vmf - vmax, 0.f) + fmaxf(vmin - Vmf, 0.f);
    wrf(out, 2103 + b, viol, bf);
  }
  if (tid < NGEN) wrf(out, 2000 + tid, dv_[gen_b[tid]].y, bf);
  if (tid == 0) {
    int ref = refp[0];
    wrf(out, 2100, dv_[ref].x, bf);
    wrf(out, 2101, dv_[ref].y, bf);
    wrf(out, 2102, (float)rsum, bf);
  }
}

extern "C" void kernel_launch(void* const* d_in, const int* in_sizes, int n_in,
                              void* d_out, int out_size, void* d_ws, size_t ws_size,
                              hipStream_t stream) {
  const void* line_g   = d_in[0];
  const void* line_b   = d_in[1];
  const void* shunt_g  = d_in[2];
  const void* shunt_b  = d_in[3];
  const void* tap      = d_in[4];
  const void* shift    = d_in[5];
  const void* charging = d_in[6];
  const void* P_gen    = d_in[7];
  const void* V_gen    = d_in[8];
  const void* P_load   = d_in[9];
  const void* Q_load   = d_in[10];
  const void* limits   = d_in[11];
  const int* line_from = (const int*)d_in[12];
  const int* line_to   = (const int*)d_in[13];
  const int* gen_b     = (const int*)d_in[14];
  const int* load_b    = (const int*)d_in[15];
  const int* refp      = (const int*)d_in[18];

  if (ws_size < sizeof(Ws)) return;
  Ws* W = (Ws*)d_ws;

  setup_k<<<dim3(8), dim3(256), 0, stream>>>(line_g, P_gen, V_gen, P_load, Q_load,
                                             gen_b, load_b, refp, W);
  solver_k<<<dim3(1), dim3(NTH), 0, stream>>>(line_g, line_b, shunt_g, shunt_b,
                                              tap, shift, charging, limits,
                                              line_from, line_to, gen_b, refp,
                                              W, d_out);
}

// Round 7
// 4190.720 us; speedup vs baseline: 5.0103x; 1.4045x over previous
//
#include <hip/hip_runtime.h>
#include <hip/hip_bf16.h>

// ACOPF Gauss-Newton, matrix-free CGLS, single-workgroup LDS-resident solver.
// R7 = R3 arithmetic (1-hop JVP/VJP gathers, standard PCG, 2x2 block-Jacobi,
// RR-keep-p every 64, tol 1e-10) + R6's 3-barrier-phase iteration:
//   P1 stage-p | P2 JVP-gather + stage-q + delta-reduce | P3 VJP-gather +
//   gamma-reduce.  Identity bus ownership (tid==bus): per-iteration LDS
//   stores stay bank-sequential (R6's degree-sorted ownership doubled bank
//   conflicts via scattered stores and regressed 35%).

#define NBUS 1000
#define NLINE 2000
#define NE   (2*NLINE)
#define NGEN 100
#define NLOAD 500
#define NTH 1024
#define NWAVE (NTH/64)
#define MAXSTEPS 10
#define KCG_MAX 600
#define RIDGE_F 1e-6f
#define TOL_REL 1e-10

struct Ws {
  int   vm_pos[NBUS];
  int   va_pos[NBUS];
  float Pspec[NBUS];
  float Qspec[NBUS];
  float Vgb[NBUS];
};

__device__ __forceinline__ float rdf(const void* p, int i, int bf) {
  if (bf) {
    unsigned int u = ((unsigned int)(((const unsigned short*)p)[i])) << 16;
    return __uint_as_float(u);
  }
  return ((const float*)p)[i];
}
__device__ __forceinline__ void wrf(void* p, int i, float v, int bf) {
  if (bf) {
    unsigned int u = __float_as_uint(v);
    unsigned int r = (u + 0x7fffu + ((u >> 16) & 1u)) >> 16;  // RNE
    ((unsigned short*)p)[i] = (unsigned short)r;
  } else {
    ((float*)p)[i] = v;
  }
}
__device__ __forceinline__ int detect_bf(const void* p) {
  const unsigned short* h = (const unsigned short*)p;
  int ok = 1;
#pragma unroll
  for (int i = 0; i < 8; ++i) {
    float v = __uint_as_float(((unsigned int)h[i]) << 16);
    ok &= (v > 0.25f && v < 8.0f) ? 1 : 0;
  }
  return ok;
}
__device__ __forceinline__ int lbound(const int* a, int n, int v) {
  int lo = 0, hi = n;
  while (lo < hi) { int m = (lo + hi) >> 1; if (a[m] < v) lo = m + 1; else hi = m; }
  return lo;
}

struct In {
  const void *lg, *lb, *tp, *sh, *ch;
  const int *lf, *lt;
  int bf;
};
struct LineY { int f, t; float ffr, ffi, ttr, tti, ftr, fti, tfr, tfi; };

__device__ __forceinline__ LineY line_y(const In& I, int l) {
  LineY L;
  float g = rdf(I.lg, l, I.bf), b = rdf(I.lb, l, I.bf);
  float t = rdf(I.tp, l, I.bf), s = rdf(I.sh, l, I.bf);
  float c = rdf(I.ch, l, I.bf) * 0.5f;
  float sn, cs;
  __sincosf(s, &sn, &cs);
  float it = 1.0f / t, it2 = it * it;
  L.f = I.lf[l]; L.t = I.lt[l];
  L.ffr = g * it2;                 L.ffi = (b + c) * it2;
  L.ttr = g;                       L.tti = b + c;
  L.ftr = -(g * cs - b * sn) * it; L.fti = -(g * sn + b * cs) * it;
  L.tfr = -(g * cs + b * sn) * it; L.tfi = -(b * cs - g * sn) * it;
  return L;
}

__device__ __forceinline__ double blk_sum1(double v, double* red) {
#pragma unroll
  for (int o = 32; o > 0; o >>= 1) v += __shfl_down(v, o, 64);
  if ((threadIdx.x & 63) == 0) red[threadIdx.x >> 6] = v;
  __syncthreads();
  double s = 0.0;
#pragma unroll
  for (int w = 0; w < NWAVE; ++w) s += red[w];
  return s;
}

__global__ void setup_k(const void* lg, const void* Pg, const void* Vg,
                        const void* Pl, const void* Ql,
                        const int* gen_b, const int* load_b, const int* refp,
                        Ws* __restrict__ W) {
  int bf = detect_bf(lg);
  int t = blockIdx.x * blockDim.x + threadIdx.x;
  int ref = refp[0];
  if (t < NBUS) {
    int gl = lbound(gen_b, NGEN, t);
    int isg = (gl < NGEN && gen_b[gl] == t) ? 1 : 0;
    int ll = lbound(load_b, NLOAD, t);
    int isl = (ll < NLOAD && load_b[ll] == t) ? 1 : 0;
    W->vm_pos[t] = isg ? -1 : (t - gl);
    W->va_pos[t] = (t == ref) ? -1 : (t - ((t > ref) ? 1 : 0));
    float ps = 0.f, qs = 0.f;
    if (isg) ps += rdf(Pg, gl, bf);
    if (isl) { ps += rdf(Pl, ll, bf); qs += rdf(Ql, ll, bf); }
    W->Pspec[t] = ps;
    W->Qspec[t] = qs;
    W->Vgb[t] = isg ? rdf(Vg, gl, bf) : 1.0f;
  }
}

__global__ void __launch_bounds__(NTH)
solver_k(const void* lg, const void* lb, const void* shg, const void* shb,
         const void* tp, const void* sh, const void* ch, const void* limits,
         const int* lf, const int* lt, const int* gen_b, const int* refp,
         const Ws* __restrict__ W, void* __restrict__ out) {
  __shared__ int rs_[NBUS + 1];
  __shared__ int scan_[NTH];
  __shared__ int scan2_[NTH];
  __shared__ int cur_[NBUS];
  __shared__ unsigned short cidx_[NE];
  __shared__ float2 fwd_[NE];
  __shared__ float2 rev_[NE];
  __shared__ float2 ab_[NBUS];
  __shared__ float2 dv_[NBUS];
  __shared__ float2 dv2_[NBUS];
  __shared__ float2 mk_[NBUS];
  __shared__ float2 gb_[NBUS];
  __shared__ double red_[2][NWAVE];

  const int tid = threadIdx.x;
  const bool own = (tid < NBUS);
  In I;
  I.lg = lg; I.lb = lb; I.tp = tp; I.sh = sh; I.ch = ch;
  I.lf = lf; I.lt = lt;
  I.bf = detect_bf(lg);
  const int bf = I.bf;

  int vp = -1, ap = -1;
  float mng = 0.f, mnr = 0.f, Pspec = 0.f, Qspec = 0.f, Vgb = 1.f;
  if (own) {
    vp = W->vm_pos[tid]; ap = W->va_pos[tid];
    mng = (vp >= 0) ? 1.f : 0.f;
    mnr = (ap >= 0) ? 1.f : 0.f;
    Pspec = W->Pspec[tid]; Qspec = W->Qspec[tid]; Vgb = W->Vgb[tid];
    mk_[tid] = make_float2(mnr, mng);
    gb_[tid] = make_float2(rdf(shg, tid, bf), rdf(shb, tid, bf));
  }
  scan_[tid] = 0;
  __syncthreads();
  for (int l = tid; l < NLINE; l += NTH) {
    atomicAdd(&scan_[lf[l]], 1);
    atomicAdd(&scan_[lt[l]], 1);
  }
  __syncthreads();
  {
    int* src = scan_; int* dst = scan2_;
    for (int off = 1; off < NTH; off <<= 1) {
      int v = src[tid] + ((tid >= off) ? src[tid - off] : 0);
      dst[tid] = v;
      __syncthreads();
      int* t = src; src = dst; dst = t;
    }
    if (tid == 0) rs_[0] = 0;
    if (own) rs_[tid + 1] = src[tid];
  }
  __syncthreads();
  if (own) cur_[tid] = rs_[tid];
  __syncthreads();
  for (int l = tid; l < NLINE; l += NTH) {
    LineY L = line_y(I, l);
    int pf = atomicAdd(&cur_[L.f], 1);
    cidx_[pf] = (unsigned short)L.t;
    fwd_[pf] = make_float2(L.ftr, L.fti);
    rev_[pf] = make_float2(L.tfr, L.tfi);
    int pt = atomicAdd(&cur_[L.t], 1);
    cidx_[pt] = (unsigned short)L.f;
    fwd_[pt] = make_float2(L.tfr, L.tfi);
    rev_[pt] = make_float2(L.ftr, L.fti);
    atomicAdd(&gb_[L.f].x, L.ffr); atomicAdd(&gb_[L.f].y, L.ffi);
    atomicAdd(&gb_[L.t].x, L.ttr); atomicAdd(&gb_[L.t].y, L.tti);
  }
  __syncthreads();
  float Gkk = 0.f, Bkk = 0.f;
  int rs0 = 0, rs1 = 0;
  if (own) { Gkk = gb_[tid].x; Bkk = gb_[tid].y; rs0 = rs_[tid]; rs1 = rs_[tid + 1]; }
  __syncthreads();

  float xvm = 1.f, xva = 0.f;
  int par = 0;

  for (int outer = 0; outer < MAXSTEPS; ++outer) {
    float av = 0.f, bv = 0.f, ca = 1.f, sa = 0.f;
    if (own) {
      float Vm = (vp >= 0) ? xvm : Vgb;
      float Va = (ap >= 0) ? xva : 0.f;
      __sincosf(Va, &sa, &ca);
      av = Vm * ca; bv = Vm * sa;
      ab_[tid] = make_float2(av, bv);
    }
    __syncthreads();
    float cI = 0.f, dI = 0.f, wPp = 0.f, wQq = 0.f;
    float M11 = 0.f, M12 = 0.f, M22 = 0.f;
    if (own) {
      cI = Gkk * av - Bkk * bv; dI = Gkk * bv + Bkk * av;
      for (int e = rs0; e < rs1; ++e) {
        int j = cidx_[e]; float2 f = fwd_[e], v = ab_[j];
        cI += f.x * v.x - f.y * v.y; dI += f.x * v.y + f.y * v.x;
      }
      float P = av * cI + bv * dI - Pspec;
      float Q = bv * cI - av * dI - Qspec;
      wPp = mnr * P; wQq = mng * Q;
      dv_[tid] = make_float2(wPp * av + wQq * bv, wPp * bv - wQq * av);
      float w1r = ca * cI + sa * dI, w1i = sa * cI - ca * dI;
      float mr = Gkk * ca - Bkk * sa, mi = -(Gkk * sa + Bkk * ca);
      float ur0 = av * mr - bv * mi, ui0 = av * mi + bv * mr;
      float Tr = w1r + ur0, Ti = w1i + ui0;
      float w2r = av * dI - bv * cI, w2i = av * cI + bv * dI;
      float wr0 = Gkk * av - Bkk * bv, wi0 = Gkk * bv + Bkk * av;
      float zr0 = av * wr0 + bv * wi0, zi0 = bv * wr0 - av * wi0;
      float Uor = w2r + zi0, Uoi = w2i - zr0;
      float Avv = mnr * Tr * Tr + mng * Ti * Ti;
      float Aaa = mnr * Uor * Uor + mng * Uoi * Uoi;
      float Ava = mnr * Tr * Uor + mng * Ti * Uoi;
      for (int e = rs0; e < rs1; ++e) {
        int j = cidx_[e]; float2 r = rev_[e], vj = ab_[j], mj = mk_[j];
        float mrr = r.x * ca - r.y * sa, mii = -(r.x * sa + r.y * ca);
        float ur = vj.x * mrr - vj.y * mii, ui = vj.x * mii + vj.y * mrr;
        float wr = r.x * av - r.y * bv, wi = r.x * bv + r.y * av;
        float zr = vj.x * wr + vj.y * wi, zi = vj.y * wr - vj.x * wi;
        Avv += mj.x * ur * ur + mj.y * ui * ui;
        Aaa += mj.x * zi * zi + mj.y * zr * zr;
        Ava += mj.x * ur * zi - mj.y * ui * zr;
      }
      float A11 = Avv + RIDGE_F, A22 = Aaa + RIDGE_F;
      if (vp >= 0 && ap >= 0) {
        float id = 1.f / (A11 * A22 - Ava * Ava);
        M11 = A22 * id; M22 = A11 * id; M12 = -Ava * id;
      } else if (vp >= 0) M11 = 1.f / A11;
      else if (ap >= 0)  M22 = 1.f / A22;
    }
    __syncthreads();
    float g0vm = 0.f, g0va = 0.f;
    if (own) {
      float cb = wPp * av + wQq * bv, db2 = wPp * bv - wQq * av;
      float sda = wPp * cI - wQq * dI + Gkk * cb + Bkk * db2;
      float sdb = wPp * dI + wQq * cI - Bkk * cb + Gkk * db2;
      for (int e = rs0; e < rs1; ++e) {
        int j = cidx_[e]; float2 r = rev_[e], w = dv_[j];
        sda += r.x * w.x + r.y * w.y; sdb += -r.y * w.x + r.x * w.y;
      }
      g0vm = mng * (ca * sda + sa * sdb);
      g0va = mnr * (-bv * sda + av * sdb);
    }
    float rvm = g0vm, rva = g0va, dxvm = 0.f, dxva = 0.f;
    float zvm = M11 * rvm + M12 * rva, zva = M12 * rvm + M22 * rva;
    float pvm = zvm, pva = zva;
    double part = own ? ((double)rvm * zvm + (double)rva * zva) : 0.0;
    double gamma = blk_sum1(part, red_[par]); par ^= 1;
    const double gamma0 = gamma;

    if (gamma0 > 0.0) {
      for (int it = 0; it < KCG_MAX; ++it) {
        float da = 0.f, db = 0.f;
        if (own) {
          da = pvm * ca - pva * bv;
          db = pvm * sa + pva * av;
          dv_[tid] = make_float2(da, db);
        }
        __syncthreads();
        float qP = 0.f, qQ = 0.f;
        double dpart = 0.0;
        if (own) {
          float dc = Gkk * da - Bkk * db, dd = Gkk * db + Bkk * da;
          for (int e = rs0; e < rs1; ++e) {
            int j = cidx_[e]; float2 f = fwd_[e], v = dv_[j];
            dc += f.x * v.x - f.y * v.y; dd += f.x * v.y + f.y * v.x;
          }
          float dP = da * cI + av * dc + db * dI + bv * dd;
          float dQ = db * cI + bv * dc - da * dI - av * dd;
          qP = mnr * dP; qQ = mng * dQ;
          dv2_[tid] = make_float2(qP * av + qQ * bv, qP * bv - qQ * av);
          dpart = (double)qP * dP + (double)qQ * dQ +
                  (double)RIDGE_F * ((double)pvm * pvm + (double)pva * pva);
        }
        double delta = blk_sum1(dpart, red_[par]); par ^= 1;
        if (!(delta > 0.0)) break;
        float af = (float)(gamma / delta);
        if (own) {
          dxvm += af * pvm; dxva += af * pva;
          float cb = qP * av + qQ * bv, db2 = qP * bv - qQ * av;
          float sda = qP * cI - qQ * dI + Gkk * cb + Bkk * db2;
          float sdb = qP * dI + qQ * cI - Bkk * cb + Gkk * db2;
          for (int e = rs0; e < rs1; ++e) {
            int j = cidx_[e]; float2 r = rev_[e], w = dv2_[j];
            sda += r.x * w.x + r.y * w.y; sdb += -r.y * w.x + r.x * w.y;
          }
          float yvm = mng * (ca * sda + sa * sdb);
          float yva = mnr * (-bv * sda + av * sdb);
          rvm -= af * (yvm + RIDGE_F * pvm);
          rva -= af * (yva + RIDGE_F * pva);
        }
        if ((it & 63) == 63) {
          __syncthreads();
          float tda = 0.f, tdb = 0.f;
          if (own) {
            tda = dxvm * ca - dxva * bv;
            tdb = dxvm * sa + dxva * av;
            dv_[tid] = make_float2(tda, tdb);
          }
          __syncthreads();
          float rqP = 0.f, rqQ = 0.f;
          if (own) {
            float dc = Gkk * tda - Bkk * tdb, dd = Gkk * tdb + Bkk * tda;
            for (int e = rs0; e < rs1; ++e) {
              int j = cidx_[e]; float2 f = fwd_[e], v = dv_[j];
              dc += f.x * v.x - f.y * v.y; dd += f.x * v.y + f.y * v.x;
            }
            float dP = tda * cI + av * dc + tdb * dI + bv * dd;
            float dQ = tdb * cI + bv * dc - tda * dI - av * dd;
            rqP = mnr * dP; rqQ = mng * dQ;
            dv2_[tid] = make_float2(rqP * av + rqQ * bv, rqP * bv - rqQ * av);
          }
          __syncthreads();
          if (own) {
            float cb = rqP * av + rqQ * bv, db2 = rqP * bv - rqQ * av;
            float sda = rqP * cI - rqQ * dI + Gkk * cb + Bkk * db2;
            float sdb = rqP * dI + rqQ * cI - Bkk * cb + Gkk * db2;
            for (int e = rs0; e < rs1; ++e) {
              int j = cidx_[e]; float2 r = rev_[e], w = dv2_[j];
              sda += r.x * w.x + r.y * w.y; sdb += -r.y * w.x + r.x * w.y;
            }
            float tvm = mng * (ca * sda + sa * sdb);
            float tva = mnr * (-bv * sda + av * sdb);
            rvm = g0vm - tvm - RIDGE_F * dxvm;
            rva = g0va - tva - RIDGE_F * dxva;
          }
        }
        double gpart = 0.0;
        if (own) {
          zvm = M11 * rvm + M12 * rva; zva = M12 * rvm + M22 * rva;
          gpart = (double)rvm * zvm + (double)rva * zva;
        }
        double gamma2 = blk_sum1(gpart, red_[par]); par ^= 1;
        if (gamma2 <= gamma0 * TOL_REL || !(gamma2 > 0.0)) break;
        float bfac = (float)(gamma2 / gamma);
        pvm = zvm + bfac * pvm; pva = zva + bfac * pva;
        gamma = gamma2;
      }
    }
    if (own) { xvm -= dxvm; xva -= dxva; }
    __syncthreads();
  }

  float Vmf = 1.f, Vaf = 0.f, av = 0.f, bv = 0.f, cI = 0.f, dI = 0.f;
  if (own) {
    Vmf = (vp >= 0) ? xvm : Vgb;
    Vaf = (ap >= 0) ? xva : 0.f;
    float sn, cs;
    __sincosf(Vaf, &sn, &cs);
    av = Vmf * cs; bv = Vmf * sn;
    ab_[tid] = make_float2(av, bv);
  }
  __syncthreads();
  float P = 0.f, Q = 0.f;
  if (own) {
    cI = Gkk * av - Bkk * bv; dI = Gkk * bv + Bkk * av;
    for (int e = rs0; e < rs1; ++e) {
      int j = cidx_[e]; float2 f = fwd_[e], v = ab_[j];
      cI += f.x * v.x - f.y * v.y; dI += f.x * v.y + f.y * v.x;
    }
    P = av * cI + bv * dI - Pspec;
    Q = bv * cI - av * dI - Qspec;
    dv_[tid] = make_float2(P, Q);
  }
  __syncthreads();
  double rpart = own ? (double)(mnr * P * P + mng * Q * Q) : 0.0;
  double rsum = blk_sum1(rpart, red_[par]); par ^= 1;
  if (own) {
    wrf(out, tid, Vmf, bf);
    wrf(out, NBUS + tid, Vaf, bf);
    float vmin = rdf(limits, 2 * tid, bf), vmax = rdf(limits, 2 * tid + 1, bf);
    float viol = fmaxf(Vmf - vmax, 0.f) + fmaxf(vmin - Vmf, 0.f);
    wrf(out, 2103 + tid, viol, bf);
  }
  if (tid < NGEN) wrf(out, 2000 + tid, dv_[gen_b[tid]].y, bf);
  if (tid == 0) {
    int ref = refp[0];
    wrf(out, 2100, dv_[ref].x, bf);
    wrf(out, 2101, dv_[ref].y, bf);
    wrf(out, 2102, (float)rsum, bf);
  }
}

extern "C" void kernel_launch(void* const* d_in, const int* in_sizes, int n_in,
                              void* d_out, int out_size, void* d_ws, size_t ws_size,
                              hipStream_t stream) {
  const void* line_g   = d_in[0];
  const void* line_b   = d_in[1];
  const void* shunt_g  = d_in[2];
  const void* shunt_b  = d_in[3];
  const void* tap      = d_in[4];
  const void* shift    = d_in[5];
  const void* charging = d_in[6];
  const void* P_gen    = d_in[7];
  const void* V_gen    = d_in[8];
  const void* P_load   = d_in[9];
  const void* Q_load   = d_in[10];
  const void* limits   = d_in[11];
  const int* line_from = (const int*)d_in[12];
  const int* line_to   = (const int*)d_in[13];
  const int* gen_b     = (const int*)d_in[14];
  const int* load_b    = (const int*)d_in[15];
  const int* refp      = (const int*)d_in[18];

  if (ws_size < sizeof(Ws)) return;
  Ws* W = (Ws*)d_ws;

  setup_k<<<dim3(8), dim3(256), 0, stream>>>(line_g, P_gen, V_gen, P_load, Q_load,
                                             gen_b, load_b, refp, W);
  solver_k<<<dim3(1), dim3(NTH), 0, stream>>>(line_g, line_b, shunt_g, shunt_b,
                                              tap, shift, charging, limits,
                                              line_from, line_to, gen_b, refp,
                                              W, d_out);
}

// Round 8
// 4017.124 us; speedup vs baseline: 5.2268x; 1.0432x over previous
//
#include <hip/hip_runtime.h>
#include <hip/hip_bf16.h>

// ACOPF Gauss-Newton, matrix-free CGLS, single-workgroup LDS-resident solver.
// R8 = R7 arithmetic (standard PCG, 2x2 block-Jacobi, RR-keep-p/64, tol 1e-10)
// with the operator apply split into:
//   edge phase: 4000 edge products, strided over 1024 threads (<=4 each,
//               perfectly balanced, independent) -> ev_[e]
//   bus phase:  contiguous row-sum of ev_ (no indirection, no dep chain)
// R7's bus-gather loops ran max-degree (~11-15) exec-masked iterations per
// wave with 2-level dependent LDS chains -> ~54% single-CU VALU busy. This
// balances the work at the cost of 5 cheap barriers/iter.

#define NBUS 1000
#define NLINE 2000
#define NE   (2*NLINE)
#define NGEN 100
#define NLOAD 500
#define NTH 1024
#define NWAVE (NTH/64)
#define MAXSTEPS 10
#define KCG_MAX 600
#define RIDGE_F 1e-6f
#define TOL_REL 1e-10

struct Ws {
  int   vm_pos[NBUS];
  int   va_pos[NBUS];
  float Pspec[NBUS];
  float Qspec[NBUS];
  float Vgb[NBUS];
};

__device__ __forceinline__ float rdf(const void* p, int i, int bf) {
  if (bf) {
    unsigned int u = ((unsigned int)(((const unsigned short*)p)[i])) << 16;
    return __uint_as_float(u);
  }
  return ((const float*)p)[i];
}
__device__ __forceinline__ void wrf(void* p, int i, float v, int bf) {
  if (bf) {
    unsigned int u = __float_as_uint(v);
    unsigned int r = (u + 0x7fffu + ((u >> 16) & 1u)) >> 16;  // RNE
    ((unsigned short*)p)[i] = (unsigned short)r;
  } else {
    ((float*)p)[i] = v;
  }
}
__device__ __forceinline__ int detect_bf(const void* p) {
  const unsigned short* h = (const unsigned short*)p;
  int ok = 1;
#pragma unroll
  for (int i = 0; i < 8; ++i) {
    float v = __uint_as_float(((unsigned int)h[i]) << 16);
    ok &= (v > 0.25f && v < 8.0f) ? 1 : 0;
  }
  return ok;
}
__device__ __forceinline__ int lbound(const int* a, int n, int v) {
  int lo = 0, hi = n;
  while (lo < hi) { int m = (lo + hi) >> 1; if (a[m] < v) lo = m + 1; else hi = m; }
  return lo;
}

struct In {
  const void *lg, *lb, *tp, *sh, *ch;
  const int *lf, *lt;
  int bf;
};
struct LineY { int f, t; float ffr, ffi, ttr, tti, ftr, fti, tfr, tfi; };

__device__ __forceinline__ LineY line_y(const In& I, int l) {
  LineY L;
  float g = rdf(I.lg, l, I.bf), b = rdf(I.lb, l, I.bf);
  float t = rdf(I.tp, l, I.bf), s = rdf(I.sh, l, I.bf);
  float c = rdf(I.ch, l, I.bf) * 0.5f;
  float sn, cs;
  __sincosf(s, &sn, &cs);
  float it = 1.0f / t, it2 = it * it;
  L.f = I.lf[l]; L.t = I.lt[l];
  L.ffr = g * it2;                 L.ffi = (b + c) * it2;
  L.ttr = g;                       L.tti = b + c;
  L.ftr = -(g * cs - b * sn) * it; L.fti = -(g * sn + b * cs) * it;
  L.tfr = -(g * cs + b * sn) * it; L.tfi = -(b * cs - g * sn) * it;
  return L;
}

__device__ __forceinline__ double blk_sum1(double v, double* red) {
#pragma unroll
  for (int o = 32; o > 0; o >>= 1) v += __shfl_down(v, o, 64);
  if ((threadIdx.x & 63) == 0) red[threadIdx.x >> 6] = v;
  __syncthreads();
  double s = 0.0;
#pragma unroll
  for (int w = 0; w < NWAVE; ++w) s += red[w];
  return s;
}

__global__ void setup_k(const void* lg, const void* Pg, const void* Vg,
                        const void* Pl, const void* Ql,
                        const int* gen_b, const int* load_b, const int* refp,
                        Ws* __restrict__ W) {
  int bf = detect_bf(lg);
  int t = blockIdx.x * blockDim.x + threadIdx.x;
  int ref = refp[0];
  if (t < NBUS) {
    int gl = lbound(gen_b, NGEN, t);
    int isg = (gl < NGEN && gen_b[gl] == t) ? 1 : 0;
    int ll = lbound(load_b, NLOAD, t);
    int isl = (ll < NLOAD && load_b[ll] == t) ? 1 : 0;
    W->vm_pos[t] = isg ? -1 : (t - gl);
    W->va_pos[t] = (t == ref) ? -1 : (t - ((t > ref) ? 1 : 0));
    float ps = 0.f, qs = 0.f;
    if (isg) ps += rdf(Pg, gl, bf);
    if (isl) { ps += rdf(Pl, ll, bf); qs += rdf(Ql, ll, bf); }
    W->Pspec[t] = ps;
    W->Qspec[t] = qs;
    W->Vgb[t] = isg ? rdf(Vg, gl, bf) : 1.0f;
  }
}

__global__ void __launch_bounds__(NTH)
solver_k(const void* lg, const void* lb, const void* shg, const void* shb,
         const void* tp, const void* sh, const void* ch, const void* limits,
         const int* lf, const int* lt, const int* gen_b, const int* refp,
         const Ws* __restrict__ W, void* __restrict__ out) {
  __shared__ int rs_[NBUS + 1];
  __shared__ unsigned short cidx_[NE];  // edge -> source-bus index
  __shared__ float2 fwd_[NE];           // Y_kj for edge in row k
  __shared__ float2 rev_[NE];           // Y_jk
  __shared__ float2 ev_[NE];            // per-edge values (overlaid at setup)
  __shared__ float2 st_[NBUS];          // per-bus staging (T(p)/qseed/T(z)/PQ)
  __shared__ float2 ab_[NBUS];          // per-bus V (re,im)
  __shared__ float2 mk_[NBUS];          // (mnr, mng)
  __shared__ float2 gb_[NBUS];          // diag Y_kk
  __shared__ double red_[2][NWAVE];

  const int tid = threadIdx.x;
  const bool own = (tid < NBUS);
  In I;
  I.lg = lg; I.lb = lb; I.tp = tp; I.sh = sh; I.ch = ch;
  I.lf = lf; I.lt = lt;
  I.bf = detect_bf(lg);
  const int bf = I.bf;

  // setup scratch overlaid on ev_ (float2[4000] = 8000 floats >= 3048 ints)
  int* scanA = (int*)ev_;
  int* scanB = ((int*)ev_) + NTH;
  int* cur_  = ((int*)ev_) + 2 * NTH;

  int vp = -1, ap = -1;
  float mng = 0.f, mnr = 0.f, Pspec = 0.f, Qspec = 0.f, Vgb = 1.f;
  if (own) {
    vp = W->vm_pos[tid]; ap = W->va_pos[tid];
    mng = (vp >= 0) ? 1.f : 0.f;
    mnr = (ap >= 0) ? 1.f : 0.f;
    Pspec = W->Pspec[tid]; Qspec = W->Qspec[tid]; Vgb = W->Vgb[tid];
    mk_[tid] = make_float2(mnr, mng);
    gb_[tid] = make_float2(rdf(shg, tid, bf), rdf(shb, tid, bf));
  }
  scanA[tid] = 0;
  __syncthreads();
  for (int l = tid; l < NLINE; l += NTH) {
    atomicAdd(&scanA[lf[l]], 1);
    atomicAdd(&scanA[lt[l]], 1);
  }
  __syncthreads();
  {
    int* src = scanA; int* dst = scanB;
    for (int off = 1; off < NTH; off <<= 1) {
      int v = src[tid] + ((tid >= off) ? src[tid - off] : 0);
      dst[tid] = v;
      __syncthreads();
      int* t = src; src = dst; dst = t;
    }
    if (tid == 0) rs_[0] = 0;
    if (own) rs_[tid + 1] = src[tid];
  }
  __syncthreads();
  if (own) cur_[tid] = rs_[tid];
  __syncthreads();
  for (int l = tid; l < NLINE; l += NTH) {
    LineY L = line_y(I, l);
    int pf = atomicAdd(&cur_[L.f], 1);
    cidx_[pf] = (unsigned short)L.t;
    fwd_[pf] = make_float2(L.ftr, L.fti);
    rev_[pf] = make_float2(L.tfr, L.tfi);
    int pt = atomicAdd(&cur_[L.t], 1);
    cidx_[pt] = (unsigned short)L.f;
    fwd_[pt] = make_float2(L.tfr, L.tfi);
    rev_[pt] = make_float2(L.ftr, L.fti);
    atomicAdd(&gb_[L.f].x, L.ffr); atomicAdd(&gb_[L.f].y, L.ffi);
    atomicAdd(&gb_[L.t].x, L.ttr); atomicAdd(&gb_[L.t].y, L.tti);
  }
  __syncthreads();
  float Gkk = 0.f, Bkk = 0.f;
  int rs0 = 0, rs1 = 0;
  if (own) { Gkk = gb_[tid].x; Bkk = gb_[tid].y; rs0 = rs_[tid]; rs1 = rs_[tid + 1]; }
  __syncthreads();   // cur_ overlay dead; ev_ free for edge values

  // edge phases: strided, balanced (<=4 edges/thread)
  #define EDGE_JVP(SRC) \
    for (int k = 0; k < 4; ++k) { \
      int e = tid + k * NTH; \
      if (e < NE) { \
        int j = cidx_[e]; float2 f = fwd_[e], v = SRC[j]; \
        ev_[e] = make_float2(f.x * v.x - f.y * v.y, f.x * v.y + f.y * v.x); \
      } \
    }
  #define EDGE_VJP() \
    for (int k = 0; k < 4; ++k) { \
      int e = tid + k * NTH; \
      if (e < NE) { \
        int j = cidx_[e]; float2 r = rev_[e], w = st_[j]; \
        ev_[e] = make_float2(r.x * w.x + r.y * w.y, r.x * w.y - r.y * w.x); \
      } \
    }

  float xvm = 1.f, xva = 0.f;
  int par = 0;

  for (int outer = 0; outer < MAXSTEPS; ++outer) {
    // A: stage V
    float av = 0.f, bv = 0.f, ca = 1.f, sa = 0.f;
    if (own) {
      float Vm = (vp >= 0) ? xvm : Vgb;
      float Va = (ap >= 0) ? xva : 0.f;
      __sincosf(Va, &sa, &ca);
      av = Vm * ca; bv = Vm * sa;
      ab_[tid] = make_float2(av, bv);
    }
    __syncthreads();
    // B: edge products of I = Y V
    EDGE_JVP(ab_)
    __syncthreads();
    // C: currents, residual, Gram 2x2, stage g0 seeds
    float cI = 0.f, dI = 0.f, wPp = 0.f, wQq = 0.f;
    float M11 = 0.f, M12 = 0.f, M22 = 0.f;
    if (own) {
      cI = Gkk * av - Bkk * bv; dI = Gkk * bv + Bkk * av;
      for (int e = rs0; e < rs1; ++e) { float2 v = ev_[e]; cI += v.x; dI += v.y; }
      float P = av * cI + bv * dI - Pspec;
      float Q = bv * cI - av * dI - Qspec;
      wPp = mnr * P; wQq = mng * Q;
      st_[tid] = make_float2(wPp * av + wQq * bv, wPp * bv - wQq * av);
      // block-Jacobi 2x2 of (J^T J + ridge)  (10x/solve: keep R7 gather form)
      float w1r = ca * cI + sa * dI, w1i = sa * cI - ca * dI;
      float mr = Gkk * ca - Bkk * sa, mi = -(Gkk * sa + Bkk * ca);
      float ur0 = av * mr - bv * mi, ui0 = av * mi + bv * mr;
      float Tr = w1r + ur0, Ti = w1i + ui0;
      float w2r = av * dI - bv * cI, w2i = av * cI + bv * dI;
      float wr0 = Gkk * av - Bkk * bv, wi0 = Gkk * bv + Bkk * av;
      float zr0 = av * wr0 + bv * wi0, zi0 = bv * wr0 - av * wi0;
      float Uor = w2r + zi0, Uoi = w2i - zr0;
      float Avv = mnr * Tr * Tr + mng * Ti * Ti;
      float Aaa = mnr * Uor * Uor + mng * Uoi * Uoi;
      float Ava = mnr * Tr * Uor + mng * Ti * Uoi;
      for (int e = rs0; e < rs1; ++e) {
        int j = cidx_[e]; float2 r = rev_[e], vj = ab_[j], mj = mk_[j];
        float mrr = r.x * ca - r.y * sa, mii = -(r.x * sa + r.y * ca);
        float ur = vj.x * mrr - vj.y * mii, ui = vj.x * mii + vj.y * mrr;
        float wr = r.x * av - r.y * bv, wi = r.x * bv + r.y * av;
        float zr = vj.x * wr + vj.y * wi, zi = vj.y * wr - vj.x * wi;
        Avv += mj.x * ur * ur + mj.y * ui * ui;
        Aaa += mj.x * zi * zi + mj.y * zr * zr;
        Ava += mj.x * ur * zi - mj.y * ui * zr;
      }
      float A11 = Avv + RIDGE_F, A22 = Aaa + RIDGE_F;
      if (vp >= 0 && ap >= 0) {
        float id = 1.f / (A11 * A22 - Ava * Ava);
        M11 = A22 * id; M22 = A11 * id; M12 = -Ava * id;
      } else if (vp >= 0) M11 = 1.f / A11;
      else if (ap >= 0)  M22 = 1.f / A22;
    }
    __syncthreads();
    // D: edge-VJP of g0
    EDGE_VJP()
    __syncthreads();
    // E: g0, PCG init, stage T(p0)
    float g0vm = 0.f, g0va = 0.f;
    if (own) {
      float cb = wPp * av + wQq * bv, db2 = wPp * bv - wQq * av;
      float sda = wPp * cI - wQq * dI + Gkk * cb + Bkk * db2;
      float sdb = wPp * dI + wQq * cI - Bkk * cb + Gkk * db2;
      for (int e = rs0; e < rs1; ++e) { float2 v = ev_[e]; sda += v.x; sdb += v.y; }
      g0vm = mng * (ca * sda + sa * sdb);
      g0va = mnr * (-bv * sda + av * sdb);
    }
    float rvm = g0vm, rva = g0va, dxvm = 0.f, dxva = 0.f;
    float zvm = M11 * rvm + M12 * rva, zva = M12 * rvm + M22 * rva;
    float pvm = zvm, pva = zva;
    if (own) st_[tid] = make_float2(pvm * ca - pva * bv, pvm * sa + pva * av);
    double part = own ? ((double)rvm * zvm + (double)rva * zva) : 0.0;
    double gamma = blk_sum1(part, red_[par]); par ^= 1;  // fences st_/ev_
    const double gamma0 = gamma;

    if (gamma0 > 0.0) {
      for (int it = 0; it < KCG_MAX; ++it) {
        // I1: edge-JVP of p (st_ = T(p))
        EDGE_JVP(st_)
        __syncthreads();
        // I2: row-sum, q rows, stage q seeds, delta-reduce
        float qP = 0.f, qQ = 0.f;
        double dpart = 0.0;
        if (own) {
          float da = pvm * ca - pva * bv;
          float db = pvm * sa + pva * av;
          float dc = Gkk * da - Bkk * db, dd = Gkk * db + Bkk * da;
          for (int e = rs0; e < rs1; ++e) { float2 v = ev_[e]; dc += v.x; dd += v.y; }
          float dP = da * cI + av * dc + db * dI + bv * dd;
          float dQ = db * cI + bv * dc - da * dI - av * dd;
          qP = mnr * dP; qQ = mng * dQ;
          st_[tid] = make_float2(qP * av + qQ * bv, qP * bv - qQ * av);
          dpart = (double)qP * dP + (double)qQ * dQ +
                  (double)RIDGE_F * ((double)pvm * pvm + (double)pva * pva);
        }
        double delta = blk_sum1(dpart, red_[par]); par ^= 1;
        if (!(delta > 0.0)) break;
        float af = (float)(gamma / delta);
        // I3: edge-VJP of q
        EDGE_VJP()
        __syncthreads();
        // I4: row-sum, r/dx update, (RR), z, gamma-reduce
        if (own) {
          dxvm += af * pvm; dxva += af * pva;
          float cb = qP * av + qQ * bv, db2 = qP * bv - qQ * av;
          float sda = qP * cI - qQ * dI + Gkk * cb + Bkk * db2;
          float sdb = qP * dI + qQ * cI - Bkk * cb + Gkk * db2;
          for (int e = rs0; e < rs1; ++e) { float2 v = ev_[e]; sda += v.x; sdb += v.y; }
          float yvm = mng * (ca * sda + sa * sdb);
          float yva = mnr * (-bv * sda + av * sdb);
          rvm -= af * (yvm + RIDGE_F * pvm);
          rva -= af * (yva + RIDGE_F * pva);
        }
        if ((it & 63) == 63) {
          // residual replacement: r = g0 - (A + ridge) dx  (keep p)
          float tda = 0.f, tdb = 0.f;
          if (own) {
            tda = dxvm * ca - dxva * bv;
            tdb = dxvm * sa + dxva * av;
            st_[tid] = make_float2(tda, tdb);
          }
          __syncthreads();
          EDGE_JVP(st_)
          __syncthreads();
          float rqP = 0.f, rqQ = 0.f;
          if (own) {
            float dc = Gkk * tda - Bkk * tdb, dd = Gkk * tdb + Bkk * tda;
            for (int e = rs0; e < rs1; ++e) { float2 v = ev_[e]; dc += v.x; dd += v.y; }
            float dP = tda * cI + av * dc + tdb * dI + bv * dd;
            float dQ = tdb * cI + bv * dc - tda * dI - av * dd;
            rqP = mnr * dP; rqQ = mng * dQ;
            st_[tid] = make_float2(rqP * av + rqQ * bv, rqP * bv - rqQ * av);
          }
          __syncthreads();
          EDGE_VJP()
          __syncthreads();
          if (own) {
            float cb = rqP * av + rqQ * bv, db2 = rqP * bv - rqQ * av;
            float sda = rqP * cI - rqQ * dI + Gkk * cb + Bkk * db2;
            float sdb = rqP * dI + rqQ * cI - Bkk * cb + Gkk * db2;
            for (int e = rs0; e < rs1; ++e) { float2 v = ev_[e]; sda += v.x; sdb += v.y; }
            float tvm = mng * (ca * sda + sa * sdb);
            float tva = mnr * (-bv * sda + av * sdb);
            rvm = g0vm - tvm - RIDGE_F * dxvm;
            rva = g0va - tva - RIDGE_F * dxva;
          }
        }
        double gpart = 0.0;
        if (own) {
          zvm = M11 * rvm + M12 * rva; zva = M12 * rvm + M22 * rva;
          gpart = (double)rvm * zvm + (double)rva * zva;
        }
        double gamma2 = blk_sum1(gpart, red_[par]); par ^= 1;
        if (gamma2 <= gamma0 * TOL_REL || !(gamma2 > 0.0)) break;
        float bfac = (float)(gamma2 / gamma);
        pvm = zvm + bfac * pvm; pva = zva + bfac * pva;
        gamma = gamma2;
        // I5: stage T(p_new) for next I1
        if (own) st_[tid] = make_float2(pvm * ca - pva * bv, pvm * sa + pva * av);
        __syncthreads();
      }
    }
    if (own) { xvm -= dxvm; xva -= dxva; }
    __syncthreads();
  }

  // ---- final outputs ----
  float Vmf = 1.f, Vaf = 0.f, av = 0.f, bv = 0.f, cI = 0.f, dI = 0.f;
  if (own) {
    Vmf = (vp >= 0) ? xvm : Vgb;
    Vaf = (ap >= 0) ? xva : 0.f;
    float sn, cs;
    __sincosf(Vaf, &sn, &cs);
    av = Vmf * cs; bv = Vmf * sn;
    ab_[tid] = make_float2(av, bv);
  }
  __syncthreads();
  EDGE_JVP(ab_)
  __syncthreads();
  float P = 0.f, Q = 0.f;
  if (own) {
    cI = Gkk * av - Bkk * bv; dI = Gkk * bv + Bkk * av;
    for (int e = rs0; e < rs1; ++e) { float2 v = ev_[e]; cI += v.x; dI += v.y; }
    P = av * cI + bv * dI - Pspec;
    Q = bv * cI - av * dI - Qspec;
    st_[tid] = make_float2(P, Q);
  }
  __syncthreads();
  double rpart = own ? (double)(mnr * P * P + mng * Q * Q) : 0.0;
  double rsum = blk_sum1(rpart, red_[par]); par ^= 1;
  if (own) {
    wrf(out, tid, Vmf, bf);
    wrf(out, NBUS + tid, Vaf, bf);
    float vmin = rdf(limits, 2 * tid, bf), vmax = rdf(limits, 2 * tid + 1, bf);
    float viol = fmaxf(Vmf - vmax, 0.f) + fmaxf(vmin - Vmf, 0.f);
    wrf(out, 2103 + tid, viol, bf);
  }
  if (tid < NGEN) wrf(out, 2000 + tid, st_[gen_b[tid]].y, bf);
  if (tid == 0) {
    int ref = refp[0];
    wrf(out, 2100, st_[ref].x, bf);
    wrf(out, 2101, st_[ref].y, bf);
    wrf(out, 2102, (float)rsum, bf);
  }
}

extern "C" void kernel_launch(void* const* d_in, const int* in_sizes, int n_in,
                              void* d_out, int out_size, void* d_ws, size_t ws_size,
                              hipStream_t stream) {
  const void* line_g   = d_in[0];
  const void* line_b   = d_in[1];
  const void* shunt_g  = d_in[2];
  const void* shunt_b  = d_in[3];
  const void* tap      = d_in[4];
  const void* shift    = d_in[5];
  const void* charging = d_in[6];
  const void* P_gen    = d_in[7];
  const void* V_gen    = d_in[8];
  const void* P_load   = d_in[9];
  const void* Q_load   = d_in[10];
  const void* limits   = d_in[11];
  const int* line_from = (const int*)d_in[12];
  const int* line_to   = (const int*)d_in[13];
  const int* gen_b     = (const int*)d_in[14];
  const int* load_b    = (const int*)d_in[15];
  const int* refp      = (const int*)d_in[18];

  if (ws_size < sizeof(Ws)) return;
  Ws* W = (Ws*)d_ws;

  setup_k<<<dim3(8), dim3(256), 0, stream>>>(line_g, P_gen, V_gen, P_load, Q_load,
                                             gen_b, load_b, refp, W);
  solver_k<<<dim3(1), dim3(NTH), 0, stream>>>(line_g, line_b, shunt_g, shunt_b,
                                              tap, shift, charging, limits,
                                              line_from, line_to, gen_b, refp,
                                              W, d_out);
}